// Round 4
// baseline (101.840 us; speedup 1.0000x reference)
//
#include <hip/hip_runtime.h>

// LocNet2d on MFMA fp16: 3 locally-connected blocks + linear head.
// repack: w2 fp32 [o][c][p][q][f] -> w2h fp16 [s=p*2+q][o][k=c*16+f] (contiguous rows)
// L1: per-patch GEMM (64 patches, M=128,N=512,K=48 pad 64) -> A2 fp16 [s][b][k2=o*16+g]
// L2: per-s GEMM M=128,N=512,K=8192, splitK=nkc2 -> P2 fp32 -> reduce -> A3 fp16 [b][o*4+s]
// L3: GEMM M=128,N=512,K=2048, splitK=nkc3 -> P3 fp32 -> fused reduce+head -> out

typedef _Float16 f16;
typedef _Float16 half8 __attribute__((ext_vector_type(8)));
typedef _Float16 half4 __attribute__((ext_vector_type(4)));
typedef float f32x4 __attribute__((ext_vector_type(4)));

// LDS half-index swizzle: rows are 64 halves (128 B); XOR bits 3-5 with row&7.
#define SWZ(r, c) ((((r) << 6) + (c)) ^ (((r) & 7) << 3))

__global__ __launch_bounds__(256) void repack_w2(const float* __restrict__ w2,
                                                 f16* __restrict__ w2h) {
  // one float4 per thread; 512*32768/4 = 4,194,304 threads = 16384 blocks x 256
  size_t idx = (size_t)blockIdx.x * 256 + threadIdx.x;
  int o = (int)(idx >> 13);       // 8192 float4 per o-row
  int off = (int)(idx & 8191) << 2;  // float offset within row
  int c = off >> 6, rem = off & 63;
  int s = rem >> 4, f0 = rem & 15;
  float4 v = *(const float4*)(w2 + ((size_t)o << 15) + off);
  half4 h;
  h[0] = (f16)v.x; h[1] = (f16)v.y; h[2] = (f16)v.z; h[3] = (f16)v.w;
  *(half4*)(w2h + ((size_t)s << 22) + ((size_t)o << 13) + c * 16 + f0) = h;
}

__global__ __launch_bounds__(256) void l1_mfma(const float* __restrict__ x,
                                               const float* __restrict__ w1,
                                               f16* __restrict__ A2) {
  // grid: (64 patches pq, 8 o-tiles). Block: 256 thr = 4 waves, tile 128b x 64o.
  const int pq = blockIdx.x, p1 = pq >> 3, q1 = pq & 7;
  const int o0 = blockIdx.y << 6;
  __shared__ __align__(16) f16 Xs[128 * 64];
  __shared__ __align__(16) f16 Ws[64 * 64];
  const int t = threadIdx.x;
#pragma unroll
  for (int i = 0; i < 8; ++i) {
    int idx = (i << 8) + t, row = idx >> 4, j = idx & 15;
    half4 h = {0, 0, 0, 0};
    if (j < 12) {
      float4 v = *(const float4*)(x + ((size_t)row * 3 + (j >> 2)) * 1024 +
                                  (p1 * 4 + (j & 3)) * 32 + q1 * 4);
      h[0] = (f16)v.x; h[1] = (f16)v.y; h[2] = (f16)v.z; h[3] = (f16)v.w;
    }
    *(half4*)&Xs[SWZ(row, j << 2)] = h;
  }
#pragma unroll
  for (int i = 0; i < 4; ++i) {
    int idx = (i << 8) + t, row = idx >> 4, j = idx & 15;
    half4 h = {0, 0, 0, 0};
    if (j < 12) {
      float4 v = *(const float4*)(w1 + (size_t)(o0 + row) * 3072 + (j >> 2) * 1024 +
                                  p1 * 128 + q1 * 16 + (j & 3) * 4);
      h[0] = (f16)v.x; h[1] = (f16)v.y; h[2] = (f16)v.z; h[3] = (f16)v.w;
    }
    *(half4*)&Ws[SWZ(row, j << 2)] = h;
  }
  __syncthreads();
  const int w = t >> 6, lane = t & 63;
  const int wr = w >> 1, wc = w & 1;
  const int frow = lane & 15, fk = (lane >> 4) << 3;
  f32x4 acc[4][2] = {};
#pragma unroll
  for (int ks = 0; ks < 2; ++ks) {
    const int col = (ks << 5) + fk;
    half8 a[4], b[2];
#pragma unroll
    for (int mi = 0; mi < 4; ++mi)
      a[mi] = *(const half8*)&Xs[SWZ(wr * 64 + mi * 16 + frow, col)];
#pragma unroll
    for (int ni = 0; ni < 2; ++ni)
      b[ni] = *(const half8*)&Ws[SWZ(wc * 32 + ni * 16 + frow, col)];
#pragma unroll
    for (int mi = 0; mi < 4; ++mi)
#pragma unroll
      for (int ni = 0; ni < 2; ++ni)
        acc[mi][ni] = __builtin_amdgcn_mfma_f32_16x16x32_f16(a[mi], b[ni], acc[mi][ni], 0, 0, 0);
  }
  const int s2 = ((p1 >> 2) << 1) + (q1 >> 2);
  const int g = ((p1 & 3) << 2) + (q1 & 3);
  f16* A2b = A2 + (size_t)s2 * 128 * 8192;
#pragma unroll
  for (int mi = 0; mi < 4; ++mi)
#pragma unroll
    for (int ni = 0; ni < 2; ++ni)
#pragma unroll
      for (int r = 0; r < 4; ++r) {
        int gm = wr * 64 + mi * 16 + (lane >> 4) * 4 + r;
        int go = o0 + wc * 32 + ni * 16 + (lane & 15);
        float v = fmaxf(acc[mi][ni][r] * 0.14433756729740643f, 0.f);  // 1/sqrt(48)
        A2b[(size_t)gm * 8192 + go * 16 + g] = (f16)v;
      }
}

// MODE 0: L2 with repacked fp16 w2h. MODE 1: L3 (fp32 w3 contiguous). MODE 2: L2 legacy fp32 gather.
template <int MODE>
__global__ __launch_bounds__(256) void gemm_f16(const f16* __restrict__ A,
                                                const void* __restrict__ Wv,
                                                float* __restrict__ P,
                                                int iters) {
  __shared__ __align__(16) f16 As[64 * 64];
  __shared__ __align__(16) f16 Bs[64 * 64];
  const int t = threadIdx.x;
  const int bid = blockIdx.x;
  constexpr int AK = (MODE == 1) ? 2048 : 8192;
  const int n = bid & 7, m = (bid >> 3) & 1;
  const int s = (MODE == 1) ? 0 : ((bid >> 4) & 3);
  const int kc = (MODE == 1) ? (bid >> 4) : (bid >> 6);
  const int kbase = kc * (iters << 6);
  const f16* Ab = A + ((size_t)((MODE == 1 ? 0 : s * 128) + m * 64)) * AK + kbase;
  const int o0 = n << 6;

  // contiguous staging coords (A always; B in MODE 0): 512 chunks of 8 halves
  const int r0 = t >> 3, sl = (t & 7) << 3, r1 = r0 + 32;
  // legacy B coords (MODE 1/2)
  const int br = t >> 4, bc = (t & 15) << 2;
  const int poff = (MODE == 2) ? ((((bid >> 4) & 3) >> 1) << 5) + ((((bid >> 4) & 3) & 1) << 4) : 0;

  const f16* Wh = (const f16*)Wv + (((size_t)s << 22) + ((size_t)o0 << 13) + kbase);
  const float* Wf = (const float*)Wv;

  uint4 a_r[2], bh_r[2];
  float4 bf_r[4];

#define LOADA(IT)                                                              \
  a_r[0] = *(const uint4*)(Ab + (size_t)r0 * AK + ((IT) << 6) + sl);           \
  a_r[1] = *(const uint4*)(Ab + (size_t)r1 * AK + ((IT) << 6) + sl);

#define LOADB(IT)                                                              \
  if constexpr (MODE == 0) {                                                   \
    bh_r[0] = *(const uint4*)(Wh + (size_t)r0 * 8192 + ((IT) << 6) + sl);      \
    bh_r[1] = *(const uint4*)(Wh + (size_t)r1 * 8192 + ((IT) << 6) + sl);      \
  } else {                                                                     \
    _Pragma("unroll") for (int i = 0; i < 4; ++i) {                            \
      int row = br + (i << 4);                                                 \
      int k = kbase + ((IT) << 6) + bc;                                        \
      const float* src = (MODE == 2)                                           \
          ? Wf + (size_t)(o0 + row) * 32768 + ((k >> 4) << 6) + poff + (k & 15)\
          : Wf + (size_t)(o0 + row) * 2048 + k;                                \
      bf_r[i] = *(const float4*)src;                                           \
    }                                                                          \
  }

  LOADA(0)
  LOADB(0)

  const int w = t >> 6, lane = t & 63;
  const int wr = w >> 1, wc = w & 1;
  const int frow = lane & 15, fk = (lane >> 4) << 3;
  f32x4 acc[2][2] = {};
  for (int it = 0; it < iters; ++it) {
    __syncthreads();  // readers of previous tile done
    *(uint4*)&As[SWZ(r0, sl)] = a_r[0];
    *(uint4*)&As[SWZ(r1, sl)] = a_r[1];
    if constexpr (MODE == 0) {
      *(uint4*)&Bs[SWZ(r0, sl)] = bh_r[0];
      *(uint4*)&Bs[SWZ(r1, sl)] = bh_r[1];
    } else {
#pragma unroll
      for (int i = 0; i < 4; ++i) {
        half4 h;
        h[0] = (f16)bf_r[i].x; h[1] = (f16)bf_r[i].y;
        h[2] = (f16)bf_r[i].z; h[3] = (f16)bf_r[i].w;
        *(half4*)&Bs[SWZ(br + (i << 4), bc)] = h;
      }
    }
    __syncthreads();
    if (it + 1 < iters) { LOADA(it + 1) LOADB(it + 1) }  // in flight during MFMA
#pragma unroll
    for (int ks = 0; ks < 2; ++ks) {
      const int col = (ks << 5) + fk;
      half8 a0 = *(const half8*)&As[SWZ(wr * 32 + frow, col)];
      half8 a1 = *(const half8*)&As[SWZ(wr * 32 + 16 + frow, col)];
      half8 b0 = *(const half8*)&Bs[SWZ(wc * 32 + frow, col)];
      half8 b1 = *(const half8*)&Bs[SWZ(wc * 32 + 16 + frow, col)];
      acc[0][0] = __builtin_amdgcn_mfma_f32_16x16x32_f16(a0, b0, acc[0][0], 0, 0, 0);
      acc[0][1] = __builtin_amdgcn_mfma_f32_16x16x32_f16(a0, b1, acc[0][1], 0, 0, 0);
      acc[1][0] = __builtin_amdgcn_mfma_f32_16x16x32_f16(a1, b0, acc[1][0], 0, 0, 0);
      acc[1][1] = __builtin_amdgcn_mfma_f32_16x16x32_f16(a1, b1, acc[1][1], 0, 0, 0);
    }
  }
  float* Pb = P + (size_t)(MODE == 1 ? kc : (kc << 2) + s) * 65536;
#pragma unroll
  for (int mi = 0; mi < 2; ++mi)
#pragma unroll
    for (int ni = 0; ni < 2; ++ni)
#pragma unroll
      for (int r = 0; r < 4; ++r) {
        int gm = (m << 6) + wr * 32 + mi * 16 + (lane >> 4) * 4 + r;
        int gn = o0 + wc * 32 + ni * 16 + (lane & 15);
        Pb[(size_t)gm * 512 + gn] = acc[mi][ni][r];
      }
#undef LOADA
#undef LOADB
}

__global__ __launch_bounds__(256) void reduce2(const float* __restrict__ P2,
                                               f16* __restrict__ A3, int nkc) {
  int idx = blockIdx.x * 256 + threadIdx.x;  // 262144 = 4s*128b*512o
  int o = idx & 511, b = (idx >> 9) & 127, s = idx >> 16;
  float v = 0.f;
  for (int kc = 0; kc < nkc; ++kc) v += P2[(size_t)((kc << 2) + s) * 65536 + b * 512 + o];
  v = fmaxf(v * 0.011048543456039805f, 0.f);  // 1/sqrt(8192)
  A3[(size_t)b * 2048 + o * 4 + s] = (f16)v;
}

__global__ __launch_bounds__(256) void out_fused(const float* __restrict__ P3,
                                                 const float* __restrict__ beta,
                                                 float* __restrict__ out, int nkc) {
  const int b = blockIdx.x, t = threadIdx.x;
  float acc = 0.f;
#pragma unroll
  for (int oi = 0; oi < 2; ++oi) {
    int o = (oi << 8) + t;
    float v = 0.f;
    for (int kc = 0; kc < nkc; ++kc) v += P3[(size_t)kc * 65536 + b * 512 + o];
    acc += fmaxf(v * 0.022097086912079608f, 0.f) * beta[o];  // 1/sqrt(2048)
  }
  __shared__ float red[4];
#pragma unroll
  for (int off = 32; off > 0; off >>= 1) acc += __shfl_down(acc, off);
  if ((t & 63) == 0) red[t >> 6] = acc;
  __syncthreads();
  if (t == 0) out[b] = (red[0] + red[1] + red[2] + red[3]) * 0.044194173824159216f;
}

extern "C" void kernel_launch(void* const* d_in, const int* in_sizes, int n_in,
                              void* d_out, int out_size, void* d_ws, size_t ws_size,
                              hipStream_t stream) {
  const float* x    = (const float*)d_in[0];
  const float* w1   = (const float*)d_in[1];
  const float* w2   = (const float*)d_in[2];
  const float* w3   = (const float*)d_in[3];
  const float* beta = (const float*)d_in[4];
  float* out = (float*)d_out;

  // adaptive sizing (deterministic given ws_size)
  auto need = [](int k2, int k3, int rp) -> size_t {
    return (8ull << 20) + ((size_t)k2 << 20) + (1ull << 19) + ((size_t)k3 << 18) +
           (rp ? (32ull << 20) : 0);
  };
  int nkc2 = 16, nkc3 = 16, rp = 1;
  while (need(nkc2, nkc3, rp) > ws_size) {
    if (nkc2 > 4) nkc2 >>= 1;
    else if (nkc3 > 4) nkc3 >>= 1;
    else if (rp) { rp = 0; nkc2 = 16; nkc3 = 16; }
    else break;
  }

  char* wsb = (char*)d_ws;
  f16*   A2 = (f16*)wsb;                                          // 8 MiB
  float* P2 = (float*)(wsb + (8ull << 20));                       // nkc2 MiB
  f16*   A3 = (f16*)(wsb + (8ull << 20) + ((size_t)nkc2 << 20));  // 0.5 MiB
  float* P3 = (float*)(wsb + (8ull << 20) + ((size_t)nkc2 << 20) + (1ull << 19));
  f16*  w2h = (f16*)(wsb + (8ull << 20) + ((size_t)nkc2 << 20) + (1ull << 19) +
                     ((size_t)nkc3 << 18));                       // 32 MiB

  const int iters2 = 8192 / 64 / nkc2;
  const int iters3 = 2048 / 64 / nkc3;

  if (rp) repack_w2<<<16384, 256, 0, stream>>>(w2, w2h);
  l1_mfma<<<dim3(64, 8), 256, 0, stream>>>(x, w1, A2);
  if (rp) gemm_f16<0><<<nkc2 * 64, 256, 0, stream>>>(A2, w2h, P2, iters2);
  else    gemm_f16<2><<<nkc2 * 64, 256, 0, stream>>>(A2, w2, P2, iters2);
  reduce2<<<1024, 256, 0, stream>>>(P2, A3, nkc2);
  gemm_f16<1><<<nkc3 * 16, 256, 0, stream>>>(A3, w3, P3, iters3);
  out_fused<<<128, 256, 0, stream>>>(P3, beta, out, nkc3);
}

// Round 5
// 81.926 us; speedup vs baseline: 1.2431x; 1.2431x over previous
//
#include <hip/hip_runtime.h>

// LocNet2d on MFMA fp16: 3 locally-connected blocks + linear head.
// L1: per-patch GEMM (64 patches, M=128,N=512,K=48 pad 64) -> A2 fp16 [s][b][k2=o*16+g]
// L2: per-s GEMM M=128,N=512,K=8192, splitK=16, K-step=128, direct fp32 w2 gather,
//     XCD-grouped (s,m) blocks -> P2 fp32 -> reduce -> A3 fp16 [b][o*4+s]
// L3: GEMM M=128,N=512,K=2048, splitK=16 -> P3 fp32 -> fused reduce+head -> out

typedef _Float16 f16;
typedef _Float16 half8 __attribute__((ext_vector_type(8)));
typedef _Float16 half4 __attribute__((ext_vector_type(4)));
typedef float f32x4 __attribute__((ext_vector_type(4)));

// 64-half (128 B) rows: XOR byte-bits 3-5 with row&7.
#define SWZ(r, c) ((((r) << 6) + (c)) ^ (((r) & 7) << 3))
// 128-half (256 B) rows: same XOR; read groups of 16 rows hit 8 distinct bank slots.
#define SWZ2(r, c) ((((r) << 7) + (c)) ^ (((r) & 7) << 3))

__global__ __launch_bounds__(256) void l1_mfma(const float* __restrict__ x,
                                               const float* __restrict__ w1,
                                               f16* __restrict__ A2) {
  // grid: (64 patches pq, 8 o-tiles). Block: 256 thr = 4 waves, tile 128b x 64o.
  const int pq = blockIdx.x, p1 = pq >> 3, q1 = pq & 7;
  const int o0 = blockIdx.y << 6;
  __shared__ __align__(16) f16 Xs[128 * 64];
  __shared__ __align__(16) f16 Ws[64 * 64];
  const int t = threadIdx.x;
#pragma unroll
  for (int i = 0; i < 8; ++i) {
    int idx = (i << 8) + t, row = idx >> 4, j = idx & 15;
    half4 h = {0, 0, 0, 0};
    if (j < 12) {
      float4 v = *(const float4*)(x + ((size_t)row * 3 + (j >> 2)) * 1024 +
                                  (p1 * 4 + (j & 3)) * 32 + q1 * 4);
      h[0] = (f16)v.x; h[1] = (f16)v.y; h[2] = (f16)v.z; h[3] = (f16)v.w;
    }
    *(half4*)&Xs[SWZ(row, j << 2)] = h;
  }
#pragma unroll
  for (int i = 0; i < 4; ++i) {
    int idx = (i << 8) + t, row = idx >> 4, j = idx & 15;
    half4 h = {0, 0, 0, 0};
    if (j < 12) {
      float4 v = *(const float4*)(w1 + (size_t)(o0 + row) * 3072 + (j >> 2) * 1024 +
                                  p1 * 128 + q1 * 16 + (j & 3) * 4);
      h[0] = (f16)v.x; h[1] = (f16)v.y; h[2] = (f16)v.z; h[3] = (f16)v.w;
    }
    *(half4*)&Ws[SWZ(row, j << 2)] = h;
  }
  __syncthreads();
  const int w = t >> 6, lane = t & 63;
  const int wr = w >> 1, wc = w & 1;
  const int frow = lane & 15, fk = (lane >> 4) << 3;
  f32x4 acc[4][2] = {};
#pragma unroll
  for (int ks = 0; ks < 2; ++ks) {
    const int col = (ks << 5) + fk;
    half8 a[4], b[2];
#pragma unroll
    for (int mi = 0; mi < 4; ++mi)
      a[mi] = *(const half8*)&Xs[SWZ(wr * 64 + mi * 16 + frow, col)];
#pragma unroll
    for (int ni = 0; ni < 2; ++ni)
      b[ni] = *(const half8*)&Ws[SWZ(wc * 32 + ni * 16 + frow, col)];
#pragma unroll
    for (int mi = 0; mi < 4; ++mi)
#pragma unroll
      for (int ni = 0; ni < 2; ++ni)
        acc[mi][ni] = __builtin_amdgcn_mfma_f32_16x16x32_f16(a[mi], b[ni], acc[mi][ni], 0, 0, 0);
  }
  const int s2 = ((p1 >> 2) << 1) + (q1 >> 2);
  const int g = ((p1 & 3) << 2) + (q1 & 3);
  f16* A2b = A2 + (size_t)s2 * 128 * 8192;
#pragma unroll
  for (int mi = 0; mi < 4; ++mi)
#pragma unroll
    for (int ni = 0; ni < 2; ++ni)
#pragma unroll
      for (int r = 0; r < 4; ++r) {
        int gm = wr * 64 + mi * 16 + (lane >> 4) * 4 + r;
        int go = o0 + wc * 32 + ni * 16 + (lane & 15);
        float v = fmaxf(acc[mi][ni][r] * 0.14433756729740643f, 0.f);  // 1/sqrt(48)
        A2b[(size_t)gm * 8192 + go * 16 + g] = (f16)v;
      }
}

// MODE 0: L2 (w2 fp32 s-gather, 1024 blocks, XCD-grouped). MODE 1: L3 (w3 fp32 contiguous, 256 blocks).
template <int MODE>
__global__ __launch_bounds__(256) void gemm_f16(const f16* __restrict__ A,
                                                const float* __restrict__ W,
                                                float* __restrict__ P) {
  __shared__ __align__(16) f16 As[64 * 128];
  __shared__ __align__(16) f16 Bs[64 * 128];
  const int t = threadIdx.x;
  const int bid = blockIdx.x;
  constexpr int AK = (MODE == 0) ? 8192 : 2048;
  constexpr int ITERS = (MODE == 0) ? 4 : 1;
  // MODE 0 decode: bid = j*128 + g; j = (m<<2)|s; g = kc*8 + n.
  // All 8 j for fixed g have bid % 8 == g % 8 -> same XCD (co-read w2 lines).
  const int j = (MODE == 0) ? (bid >> 7) : 0;
  const int g = (MODE == 0) ? (bid & 127) : bid;
  const int s = (MODE == 0) ? (j & 3) : 0;
  const int m = (MODE == 0) ? (j >> 2) : ((g >> 3) & 1);
  const int kc = (MODE == 0) ? (g >> 3) : (g >> 4);
  const int n = g & 7;
  const int kbase = kc * (ITERS * 128);
  const f16* Ab = A + ((size_t)((MODE == 0 ? s * 128 : 0) + m * 64)) * AK + kbase;
  const int o0 = n << 6;

  // A staging: 4 uint4/thread; 16 lanes read 256 B contiguous per row.
  const int ar = t >> 4, ac = (t & 15) << 3;  // + i*16 rows
  // B staging MODE 0: 8 float4/thread; 4 lanes cover one 16-float (64 B) chunk.
  const int b0r = t >> 2, b0s = (t & 3) << 2;  // row, slot; chunk from i-loop
  // B staging MODE 1: 8 float4/thread; 32 lanes cover 512 B contiguous per row.
  const int b1r = t >> 5, b1c = (t & 31) << 2;  // + i*8 rows

  uint4 a_r[4];
  float4 b_r[8];

#define LOADA(IT)                                                                \
  _Pragma("unroll") for (int i = 0; i < 4; ++i)                                  \
      a_r[i] = *(const uint4*)(Ab + (size_t)(ar + (i << 4)) * AK + ((IT) << 7) + ac);

#define LOADB(IT)                                                                \
  _Pragma("unroll") for (int i = 0; i < 8; ++i) {                                \
    const float* src = (MODE == 0)                                               \
        ? W + (size_t)(o0 + b0r) * 32768 + (((kbase + ((IT) << 7)) >> 4) + i) * 64 + \
              (s << 4) + b0s                                                     \
        : W + (size_t)(o0 + b1r + (i << 3)) * 2048 + kbase + ((IT) << 7) + b1c;  \
    b_r[i] = *(const float4*)src;                                                \
  }

  LOADA(0)
  LOADB(0)

  const int w = t >> 6, lane = t & 63;
  const int wr = w >> 1, wc = w & 1;
  const int frow = lane & 15, fk = (lane >> 4) << 3;
  f32x4 acc[2][2] = {};
  for (int it = 0; it < ITERS; ++it) {
    __syncthreads();  // readers of previous tile done
#pragma unroll
    for (int i = 0; i < 4; ++i) *(uint4*)&As[SWZ2(ar + (i << 4), ac)] = a_r[i];
#pragma unroll
    for (int i = 0; i < 8; ++i) {
      half4 h;
      h[0] = (f16)b_r[i].x; h[1] = (f16)b_r[i].y;
      h[2] = (f16)b_r[i].z; h[3] = (f16)b_r[i].w;
      if constexpr (MODE == 0)
        *(half4*)&Bs[SWZ2(b0r, (i << 4) + b0s)] = h;
      else
        *(half4*)&Bs[SWZ2(b1r + (i << 3), b1c)] = h;
    }
    __syncthreads();
    if (it + 1 < ITERS) { LOADA(it + 1) LOADB(it + 1) }  // in flight during MFMA
#pragma unroll
    for (int ks = 0; ks < 4; ++ks) {
      const int col = (ks << 5) + fk;
      half8 a0 = *(const half8*)&As[SWZ2(wr * 32 + frow, col)];
      half8 a1 = *(const half8*)&As[SWZ2(wr * 32 + 16 + frow, col)];
      half8 b0 = *(const half8*)&Bs[SWZ2(wc * 32 + frow, col)];
      half8 b1 = *(const half8*)&Bs[SWZ2(wc * 32 + 16 + frow, col)];
      acc[0][0] = __builtin_amdgcn_mfma_f32_16x16x32_f16(a0, b0, acc[0][0], 0, 0, 0);
      acc[0][1] = __builtin_amdgcn_mfma_f32_16x16x32_f16(a0, b1, acc[0][1], 0, 0, 0);
      acc[1][0] = __builtin_amdgcn_mfma_f32_16x16x32_f16(a1, b0, acc[1][0], 0, 0, 0);
      acc[1][1] = __builtin_amdgcn_mfma_f32_16x16x32_f16(a1, b1, acc[1][1], 0, 0, 0);
    }
  }
  float* Pb = P + (size_t)(MODE == 0 ? (kc << 2) + s : kc) * 65536;
#pragma unroll
  for (int mi = 0; mi < 2; ++mi)
#pragma unroll
    for (int ni = 0; ni < 2; ++ni)
#pragma unroll
      for (int r = 0; r < 4; ++r) {
        int gm = (m << 6) + wr * 32 + mi * 16 + (lane >> 4) * 4 + r;
        int gn = o0 + wc * 32 + ni * 16 + (lane & 15);
        Pb[(size_t)gm * 512 + gn] = acc[mi][ni][r];
      }
#undef LOADA
#undef LOADB
}

__global__ __launch_bounds__(256) void reduce2(const float* __restrict__ P2,
                                               f16* __restrict__ A3) {
  int idx = blockIdx.x * 256 + threadIdx.x;  // 262144 = 4s*128b*512o
  int o = idx & 511, b = (idx >> 9) & 127, s = idx >> 16;
  float v = 0.f;
#pragma unroll
  for (int kc = 0; kc < 16; ++kc) v += P2[(size_t)((kc << 2) + s) * 65536 + b * 512 + o];
  v = fmaxf(v * 0.011048543456039805f, 0.f);  // 1/sqrt(8192)
  A3[(size_t)b * 2048 + o * 4 + s] = (f16)v;
}

__global__ __launch_bounds__(256) void out_fused(const float* __restrict__ P3,
                                                 const float* __restrict__ beta,
                                                 float* __restrict__ out) {
  const int b = blockIdx.x, t = threadIdx.x;
  float acc = 0.f;
#pragma unroll
  for (int oi = 0; oi < 2; ++oi) {
    int o = (oi << 8) + t;
    float v = 0.f;
#pragma unroll
    for (int kc = 0; kc < 16; ++kc) v += P3[(size_t)kc * 65536 + b * 512 + o];
    acc += fmaxf(v * 0.022097086912079608f, 0.f) * beta[o];  // 1/sqrt(2048)
  }
  __shared__ float red[4];
#pragma unroll
  for (int off = 32; off > 0; off >>= 1) acc += __shfl_down(acc, off);
  if ((t & 63) == 0) red[t >> 6] = acc;
  __syncthreads();
  if (t == 0) out[b] = (red[0] + red[1] + red[2] + red[3]) * 0.044194173824159216f;
}

extern "C" void kernel_launch(void* const* d_in, const int* in_sizes, int n_in,
                              void* d_out, int out_size, void* d_ws, size_t ws_size,
                              hipStream_t stream) {
  const float* x    = (const float*)d_in[0];
  const float* w1   = (const float*)d_in[1];
  const float* w2   = (const float*)d_in[2];
  const float* w3   = (const float*)d_in[3];
  const float* beta = (const float*)d_in[4];
  float* out = (float*)d_out;

  char* wsb = (char*)d_ws;
  f16*   A2 = (f16*)wsb;                          // 8 MiB: 4*128*8192 fp16
  float* P2 = (float*)(wsb + (8ull << 20));       // 16 MiB: 64*128*512 fp32
  f16*   A3 = (f16*)(wsb + (24ull << 20));        // 0.5 MiB
  float* P3 = (float*)(wsb + (24ull << 20) + (1ull << 19));  // 4 MiB

  l1_mfma<<<dim3(64, 8), 256, 0, stream>>>(x, w1, A2);
  gemm_f16<0><<<1024, 256, 0, stream>>>(A2, w2, P2);
  reduce2<<<1024, 256, 0, stream>>>(P2, A3);
  gemm_f16<1><<<256, 256, 0, stream>>>(A3, w3, P3);
  out_fused<<<128, 256, 0, stream>>>(P3, beta, out);
}

// Round 6
// 59.555 us; speedup vs baseline: 1.7100x; 1.3756x over previous
//
#include <hip/hip_runtime.h>

// LocNet2d on MFMA fp16, global_load_lds staging (m97 structure).
// L1: per-patch GEMM -> A2 fp16 [s][b][k2=o*16+g]
// L2: per-s GEMM M=128,N=512,K=8192, splitK=16, K-step=128.
//     B = w2 fp32 DMA'd to LDS via per-lane gathered global_load_lds (s-interleave
//     + bank-swizzle folded into the SOURCE address; LDS dest linear).
//     A = A2 fp16 DMA'd likewise. -> P2 -> reduce -> A3 fp16 [b][o*4+s]
// L3: same structure, M=128,N=512,K=2048, splitK=16 -> P3 -> fused reduce+head.

typedef _Float16 f16;
typedef _Float16 half8 __attribute__((ext_vector_type(8)));
typedef _Float16 half4 __attribute__((ext_vector_type(4)));
typedef float f32x4 __attribute__((ext_vector_type(4)));

#define SWZ(r, c) ((((r) << 6) + (c)) ^ (((r) & 7) << 3))

#define GLOAD_LDS16(G, L)                                                     \
  __builtin_amdgcn_global_load_lds(                                           \
      (const __attribute__((address_space(1))) void*)(G),                     \
      (__attribute__((address_space(3))) void*)(L), 16, 0, 0)

__global__ __launch_bounds__(256) void l1_mfma(const float* __restrict__ x,
                                               const float* __restrict__ w1,
                                               f16* __restrict__ A2) {
  const int pq = blockIdx.x, p1 = pq >> 3, q1 = pq & 7;
  const int o0 = blockIdx.y << 6;
  __shared__ __align__(16) f16 Xs[128 * 64];
  __shared__ __align__(16) f16 Ws[64 * 64];
  const int t = threadIdx.x;
#pragma unroll
  for (int i = 0; i < 8; ++i) {
    int idx = (i << 8) + t, row = idx >> 4, j = idx & 15;
    half4 h = {0, 0, 0, 0};
    if (j < 12) {
      float4 v = *(const float4*)(x + ((size_t)row * 3 + (j >> 2)) * 1024 +
                                  (p1 * 4 + (j & 3)) * 32 + q1 * 4);
      h[0] = (f16)v.x; h[1] = (f16)v.y; h[2] = (f16)v.z; h[3] = (f16)v.w;
    }
    *(half4*)&Xs[SWZ(row, j << 2)] = h;
  }
#pragma unroll
  for (int i = 0; i < 4; ++i) {
    int idx = (i << 8) + t, row = idx >> 4, j = idx & 15;
    half4 h = {0, 0, 0, 0};
    if (j < 12) {
      float4 v = *(const float4*)(w1 + (size_t)(o0 + row) * 3072 + (j >> 2) * 1024 +
                                  p1 * 128 + q1 * 16 + (j & 3) * 4);
      h[0] = (f16)v.x; h[1] = (f16)v.y; h[2] = (f16)v.z; h[3] = (f16)v.w;
    }
    *(half4*)&Ws[SWZ(row, j << 2)] = h;
  }
  __syncthreads();
  const int w = t >> 6, lane = t & 63;
  const int wr = w >> 1, wc = w & 1;
  const int frow = lane & 15, fk = (lane >> 4) << 3;
  f32x4 acc[4][2] = {};
#pragma unroll
  for (int ks = 0; ks < 2; ++ks) {
    const int col = (ks << 5) + fk;
    half8 a[4], b[2];
#pragma unroll
    for (int mi = 0; mi < 4; ++mi)
      a[mi] = *(const half8*)&Xs[SWZ(wr * 64 + mi * 16 + frow, col)];
#pragma unroll
    for (int ni = 0; ni < 2; ++ni)
      b[ni] = *(const half8*)&Ws[SWZ(wc * 32 + ni * 16 + frow, col)];
#pragma unroll
    for (int mi = 0; mi < 4; ++mi)
#pragma unroll
      for (int ni = 0; ni < 2; ++ni)
        acc[mi][ni] = __builtin_amdgcn_mfma_f32_16x16x32_f16(a[mi], b[ni], acc[mi][ni], 0, 0, 0);
  }
  const int s2 = ((p1 >> 2) << 1) + (q1 >> 2);
  const int g = ((p1 & 3) << 2) + (q1 & 3);
  f16* A2b = A2 + (size_t)s2 * 128 * 8192;
#pragma unroll
  for (int mi = 0; mi < 4; ++mi)
#pragma unroll
    for (int ni = 0; ni < 2; ++ni)
#pragma unroll
      for (int r = 0; r < 4; ++r) {
        int gm = wr * 64 + mi * 16 + (lane >> 4) * 4 + r;
        int go = o0 + wc * 32 + ni * 16 + (lane & 15);
        float v = fmaxf(acc[mi][ni][r] * 0.14433756729740643f, 0.f);  // 1/sqrt(48)
        A2b[(size_t)gm * 8192 + go * 16 + g] = (f16)v;
      }
}

// MODE 0: L2 (w2 fp32 s-gather). MODE 1: L3 (w3 fp32 contiguous).
// Block tile: M=128 x N=64, K-step 128. LDS: As fp16 [128][128], Bs fp32 [64][128].
// Source-pre-swizzle: LDS holds slot^(row&7); reads apply the same XOR.
template <int MODE>
__global__ __launch_bounds__(256) void gemm_f16(const f16* __restrict__ A,
                                                const float* __restrict__ W,
                                                float* __restrict__ P) {
  __shared__ __align__(16) f16 As[128 * 128];    // 32 KB
  __shared__ __align__(16) float Bs[64 * 128];   // 32 KB
  const int t = threadIdx.x;
  const int bid = blockIdx.x;
  constexpr int AK = (MODE == 0) ? 8192 : 2048;
  constexpr int WROW = (MODE == 0) ? 32768 : 2048;
  constexpr int ITERS = (MODE == 0) ? 4 : 1;
  // MODE 0: bid = s*128 + kc*8 + n -> 4 s-blocks of a (kc,n) share bid%8 (same XCD).
  const int s = (MODE == 0) ? (bid >> 7) : 0;
  const int kc = (MODE == 0) ? ((bid >> 3) & 15) : (bid >> 3);
  const int n = bid & 7;
  const int kb0 = kc * (ITERS * 128);
  const f16* Ab = A + (size_t)(MODE == 0 ? s * 128 : 0) * AK + kb0;
  const int o0 = n << 6;

  const int wv = t >> 6, ln = t & 63;

#define STAGE(IT)                                                              \
  {                                                                            \
    _Pragma("unroll") for (int jj = 0; jj < 8; ++jj) {  /* A: 128 rows x 256B */ \
      int rbase = wv * 32 + jj * 4;                                            \
      int r = rbase + (ln >> 4);                                               \
      int sg = (ln & 15) ^ (r & 7);                                            \
      const f16* gp = Ab + (size_t)r * AK + ((IT) << 7) + (sg << 3);           \
      GLOAD_LDS16(gp, &As[rbase << 7]);                                        \
    }                                                                          \
    _Pragma("unroll") for (int jj = 0; jj < 8; ++jj) {  /* B: 64 rows x 512B */ \
      int rbase = wv * 16 + jj * 2;                                            \
      int r = rbase + (ln >> 5);                                               \
      int sg = (ln & 31) ^ (r & 7);                                            \
      const float* gp;                                                         \
      if constexpr (MODE == 0) {                                               \
        int kb4 = (kb0 + ((IT) << 7)) >> 4;                                    \
        gp = W + (size_t)(o0 + r) * WROW + ((kb4 + (sg >> 2)) << 6) +          \
             (s << 4) + ((sg & 3) << 2);                                       \
      } else {                                                                 \
        gp = W + (size_t)(o0 + r) * WROW + kb0 + ((IT) << 7) + (sg << 2);      \
      }                                                                        \
      GLOAD_LDS16(gp, &Bs[rbase << 7]);                                        \
    }                                                                          \
  }

  STAGE(0)

  const int wr = wv >> 1, wc = wv & 1;
  const int frow = ln & 15, fr4 = ln >> 4;
  f32x4 acc[4][2] = {};
  for (int it = 0; it < ITERS; ++it) {
    __syncthreads();  // waits vmcnt(0): staged data visible
#pragma unroll
    for (int ks = 0; ks < 4; ++ks) {
      half8 a[4];
#pragma unroll
      for (int mi = 0; mi < 4; ++mi) {
        int r = wr * 64 + mi * 16 + frow;
        int sl = ((ks << 2) + fr4) ^ (r & 7);
        a[mi] = *(const half8*)&As[(r << 7) + (sl << 3)];
      }
#pragma unroll
      for (int ni = 0; ni < 2; ++ni) {
        int r = wc * 32 + ni * 16 + frow;
        int s0 = (ks << 3) + (fr4 << 1);
        float4 f0 = *(const float4*)&Bs[(r << 7) + ((s0 ^ (r & 7)) << 2)];
        float4 f1 = *(const float4*)&Bs[(r << 7) + (((s0 + 1) ^ (r & 7)) << 2)];
        half8 hb;
        hb[0] = (f16)f0.x; hb[1] = (f16)f0.y; hb[2] = (f16)f0.z; hb[3] = (f16)f0.w;
        hb[4] = (f16)f1.x; hb[5] = (f16)f1.y; hb[6] = (f16)f1.z; hb[7] = (f16)f1.w;
#pragma unroll
        for (int mi = 0; mi < 4; ++mi)
          acc[mi][ni] = __builtin_amdgcn_mfma_f32_16x16x32_f16(a[mi], hb, acc[mi][ni], 0, 0, 0);
      }
    }
    if (it + 1 < ITERS) {
      __syncthreads();  // all waves done reading before overwrite
      STAGE(it + 1)
    }
  }
  float* Pb = P + (size_t)(MODE == 0 ? (kc << 2) + s : kc) * 65536;
#pragma unroll
  for (int mi = 0; mi < 4; ++mi)
#pragma unroll
    for (int ni = 0; ni < 2; ++ni)
#pragma unroll
      for (int r = 0; r < 4; ++r) {
        int gm = wr * 64 + mi * 16 + fr4 * 4 + r;
        int gn = o0 + wc * 32 + ni * 16 + frow;
        Pb[(size_t)gm * 512 + gn] = acc[mi][ni][r];
      }
#undef STAGE
}

__global__ __launch_bounds__(256) void reduce2(const float* __restrict__ P2,
                                               f16* __restrict__ A3) {
  int idx = blockIdx.x * 256 + threadIdx.x;  // 262144 = 4s*128b*512o
  int o = idx & 511, b = (idx >> 9) & 127, s = idx >> 16;
  float v = 0.f;
#pragma unroll
  for (int kc = 0; kc < 16; ++kc) v += P2[(size_t)((kc << 2) + s) * 65536 + b * 512 + o];
  v = fmaxf(v * 0.011048543456039805f, 0.f);  // 1/sqrt(8192)
  A3[(size_t)b * 2048 + o * 4 + s] = (f16)v;
}

__global__ __launch_bounds__(256) void out_fused(const float* __restrict__ P3,
                                                 const float* __restrict__ beta,
                                                 float* __restrict__ out) {
  const int b = blockIdx.x, t = threadIdx.x;
  float acc = 0.f;
#pragma unroll
  for (int oi = 0; oi < 2; ++oi) {
    int o = (oi << 8) + t;
    float v = 0.f;
#pragma unroll
    for (int kc = 0; kc < 16; ++kc) v += P3[(size_t)kc * 65536 + b * 512 + o];
    acc += fmaxf(v * 0.022097086912079608f, 0.f) * beta[o];  // 1/sqrt(2048)
  }
  __shared__ float red[4];
#pragma unroll
  for (int off = 32; off > 0; off >>= 1) acc += __shfl_down(acc, off);
  if ((t & 63) == 0) red[t >> 6] = acc;
  __syncthreads();
  if (t == 0) out[b] = (red[0] + red[1] + red[2] + red[3]) * 0.044194173824159216f;
}

extern "C" void kernel_launch(void* const* d_in, const int* in_sizes, int n_in,
                              void* d_out, int out_size, void* d_ws, size_t ws_size,
                              hipStream_t stream) {
  const float* x    = (const float*)d_in[0];
  const float* w1   = (const float*)d_in[1];
  const float* w2   = (const float*)d_in[2];
  const float* w3   = (const float*)d_in[3];
  const float* beta = (const float*)d_in[4];
  float* out = (float*)d_out;

  char* wsb = (char*)d_ws;
  f16*   A2 = (f16*)wsb;                          // 8 MiB: 4*128*8192 fp16
  float* P2 = (float*)(wsb + (8ull << 20));       // 16 MiB: 64*128*512 fp32
  f16*   A3 = (f16*)(wsb + (24ull << 20));        // 0.5 MiB
  float* P3 = (float*)(wsb + (24ull << 20) + (1ull << 19));  // 4 MiB

  l1_mfma<<<dim3(64, 8), 256, 0, stream>>>(x, w1, A2);
  gemm_f16<0><<<512, 256, 0, stream>>>(A2, w2, P2);
  reduce2<<<1024, 256, 0, stream>>>(P2, A3);
  gemm_f16<1><<<128, 256, 0, stream>>>(A3, w3, P3);
  out_fused<<<128, 256, 0, stream>>>(P3, beta, out);
}

// Round 7
// 58.362 us; speedup vs baseline: 1.7450x; 1.0204x over previous
//
#include <hip/hip_runtime.h>

// LocNet2d on MFMA fp16, global_load_lds staging + T3-minimum double-buffer pipeline.
// L1: per-patch GEMM -> A2 fp16 [s][b][k2=o*16+g]
// L2: per-s GEMM M=128,N=512,K=8192, splitK=16, K-step=64, LDS double-buffered,
//     prefetch-before-compute; B = w2 fp32 DMA'd via per-lane gathered global_load_lds
//     (s-interleave + bank-swizzle folded into SOURCE address; LDS dest linear).
// L3: same structure, K=2048, splitK=16 -> P3 -> fused reduce+head.

typedef _Float16 f16;
typedef _Float16 half8 __attribute__((ext_vector_type(8)));
typedef _Float16 half4 __attribute__((ext_vector_type(4)));
typedef float f32x4 __attribute__((ext_vector_type(4)));

#define SWZ(r, c) ((((r) << 6) + (c)) ^ (((r) & 7) << 3))

#define GLOAD_LDS16(G, L)                                                     \
  __builtin_amdgcn_global_load_lds(                                           \
      (const __attribute__((address_space(1))) void*)(G),                     \
      (__attribute__((address_space(3))) void*)(L), 16, 0, 0)

__global__ __launch_bounds__(256) void l1_mfma(const float* __restrict__ x,
                                               const float* __restrict__ w1,
                                               f16* __restrict__ A2) {
  const int pq = blockIdx.x, p1 = pq >> 3, q1 = pq & 7;
  const int o0 = blockIdx.y << 6;
  __shared__ __align__(16) f16 Xs[128 * 64];
  __shared__ __align__(16) f16 Ws[64 * 64];
  const int t = threadIdx.x;
#pragma unroll
  for (int i = 0; i < 8; ++i) {
    int idx = (i << 8) + t, row = idx >> 4, j = idx & 15;
    half4 h = {0, 0, 0, 0};
    if (j < 12) {
      float4 v = *(const float4*)(x + ((size_t)row * 3 + (j >> 2)) * 1024 +
                                  (p1 * 4 + (j & 3)) * 32 + q1 * 4);
      h[0] = (f16)v.x; h[1] = (f16)v.y; h[2] = (f16)v.z; h[3] = (f16)v.w;
    }
    *(half4*)&Xs[SWZ(row, j << 2)] = h;
  }
#pragma unroll
  for (int i = 0; i < 4; ++i) {
    int idx = (i << 8) + t, row = idx >> 4, j = idx & 15;
    half4 h = {0, 0, 0, 0};
    if (j < 12) {
      float4 v = *(const float4*)(w1 + (size_t)(o0 + row) * 3072 + (j >> 2) * 1024 +
                                  p1 * 128 + q1 * 16 + (j & 3) * 4);
      h[0] = (f16)v.x; h[1] = (f16)v.y; h[2] = (f16)v.z; h[3] = (f16)v.w;
    }
    *(half4*)&Ws[SWZ(row, j << 2)] = h;
  }
  __syncthreads();
  const int w = t >> 6, lane = t & 63;
  const int wr = w >> 1, wc = w & 1;
  const int frow = lane & 15, fk = (lane >> 4) << 3;
  f32x4 acc[4][2] = {};
#pragma unroll
  for (int ks = 0; ks < 2; ++ks) {
    const int col = (ks << 5) + fk;
    half8 a[4], b[2];
#pragma unroll
    for (int mi = 0; mi < 4; ++mi)
      a[mi] = *(const half8*)&Xs[SWZ(wr * 64 + mi * 16 + frow, col)];
#pragma unroll
    for (int ni = 0; ni < 2; ++ni)
      b[ni] = *(const half8*)&Ws[SWZ(wc * 32 + ni * 16 + frow, col)];
#pragma unroll
    for (int mi = 0; mi < 4; ++mi)
#pragma unroll
      for (int ni = 0; ni < 2; ++ni)
        acc[mi][ni] = __builtin_amdgcn_mfma_f32_16x16x32_f16(a[mi], b[ni], acc[mi][ni], 0, 0, 0);
  }
  const int s2 = ((p1 >> 2) << 1) + (q1 >> 2);
  const int g = ((p1 & 3) << 2) + (q1 & 3);
  f16* A2b = A2 + (size_t)s2 * 128 * 8192;
#pragma unroll
  for (int mi = 0; mi < 4; ++mi)
#pragma unroll
    for (int ni = 0; ni < 2; ++ni)
#pragma unroll
      for (int r = 0; r < 4; ++r) {
        int gm = wr * 64 + mi * 16 + (lane >> 4) * 4 + r;
        int go = o0 + wc * 32 + ni * 16 + (lane & 15);
        float v = fmaxf(acc[mi][ni][r] * 0.14433756729740643f, 0.f);  // 1/sqrt(48)
        A2b[(size_t)gm * 8192 + go * 16 + g] = (f16)v;
      }
}

// MODE 0: L2 (w2 fp32 s-gather, 512 blocks). MODE 1: L3 (w3 fp32 contiguous, 128 blocks).
// Tile M=128 x N=64, K-step 64, DOUBLE-BUFFERED LDS, prefetch-before-compute.
// As rows 128B (8 x 16B granules, swizzle g^(r&7)); Bs rows 256B fp32 (16 granules, same).
template <int MODE>
__global__ __launch_bounds__(256) void gemm_f16(const f16* __restrict__ A,
                                                const float* __restrict__ W,
                                                float* __restrict__ P) {
  __shared__ __align__(16) f16 As[2][128 * 64];   // 2 x 16 KB
  __shared__ __align__(16) float Bs[2][64 * 64];  // 2 x 16 KB
  const int t = threadIdx.x;
  const int bid = blockIdx.x;
  constexpr int AK = (MODE == 0) ? 8192 : 2048;
  constexpr int ITERS = (MODE == 0) ? 8 : 2;  // K-chunk 512 / 128, step 64
  // MODE 0: bid = s*128 + kc*8 + n -> 4 s-blocks of (kc,n) share bid%8 (same XCD).
  const int s = (MODE == 0) ? (bid >> 7) : 0;
  const int kc = (MODE == 0) ? ((bid >> 3) & 15) : (bid >> 3);
  const int n = bid & 7;
  const int kb0 = kc * (ITERS * 64);
  const f16* Ab = A + (size_t)(MODE == 0 ? s * 128 : 0) * AK + kb0;
  const int o0 = n << 6;

  const int wv = t >> 6, ln = t & 63;
  // A staging: 4 groups of 8 rows (1 KB/wave each)
  const int a_r = (ln >> 3), a_sg0 = ln & 7;
  // B staging: 4 groups of 4 rows (1 KB/wave each)
  const int b_r = (ln >> 4), b_sg0 = ln & 15;

#define STAGE(IT, BUF)                                                          \
  {                                                                             \
    _Pragma("unroll") for (int jj = 0; jj < 4; ++jj) {                          \
      int rbase = wv * 32 + jj * 8;                                             \
      int r = rbase + a_r;                                                      \
      int sg = a_sg0 ^ (r & 7);                                                 \
      GLOAD_LDS16(Ab + (size_t)r * AK + ((IT) << 6) + (sg << 3),                \
                  &As[BUF][rbase << 6]);                                        \
    }                                                                           \
    _Pragma("unroll") for (int jj = 0; jj < 4; ++jj) {                          \
      int rbase = wv * 16 + jj * 4;                                             \
      int r = rbase + b_r;                                                      \
      int sg = b_sg0 ^ (r & 7);                                                 \
      const float* gp;                                                          \
      if constexpr (MODE == 0) {                                                \
        int k = kb0 + ((IT) << 6) + (sg << 2);                                  \
        gp = W + (size_t)(o0 + r) * 32768 + ((k >> 4) << 6) + (s << 4) + (k & 15); \
      } else {                                                                  \
        gp = W + (size_t)(o0 + r) * 2048 + kb0 + ((IT) << 6) + (sg << 2);       \
      }                                                                         \
      GLOAD_LDS16(gp, &Bs[BUF][rbase << 6]);                                    \
    }                                                                           \
  }

  const int wr = wv >> 1, wc = wv & 1;
  const int frow = ln & 15, fr4 = ln >> 4;
  f32x4 acc[4][2] = {};

#define COMPUTE(BUF)                                                            \
  _Pragma("unroll") for (int ks = 0; ks < 2; ++ks) {                            \
    half8 a[4];                                                                 \
    _Pragma("unroll") for (int mi = 0; mi < 4; ++mi) {                          \
      int r = wr * 64 + mi * 16 + frow;                                         \
      int gl = ((ks << 2) + fr4) ^ (r & 7);                                     \
      a[mi] = *(const half8*)&As[BUF][(r << 6) + (gl << 3)];                    \
    }                                                                           \
    _Pragma("unroll") for (int ni = 0; ni < 2; ++ni) {                          \
      int r = wc * 32 + ni * 16 + frow;                                         \
      int s0 = (ks << 3) + (fr4 << 1);                                          \
      float4 f0 = *(const float4*)&Bs[BUF][(r << 6) + ((s0 ^ (r & 7)) << 2)];   \
      float4 f1 = *(const float4*)&Bs[BUF][(r << 6) + (((s0 + 1) ^ (r & 7)) << 2)]; \
      half8 hb;                                                                 \
      hb[0] = (f16)f0.x; hb[1] = (f16)f0.y; hb[2] = (f16)f0.z; hb[3] = (f16)f0.w; \
      hb[4] = (f16)f1.x; hb[5] = (f16)f1.y; hb[6] = (f16)f1.z; hb[7] = (f16)f1.w; \
      _Pragma("unroll") for (int mi = 0; mi < 4; ++mi)                          \
        acc[mi][ni] = __builtin_amdgcn_mfma_f32_16x16x32_f16(a[mi], hb, acc[mi][ni], 0, 0, 0); \
    }                                                                           \
  }

  STAGE(0, 0)
  __syncthreads();  // vmcnt(0): buf0 ready
#pragma unroll
  for (int it = 0; it < ITERS; ++it) {
    const int cur = it & 1;
    if (it + 1 < ITERS) STAGE(it + 1, cur ^ 1)  // in flight during compute
    COMPUTE(cur)
    __syncthreads();  // drains prefetch; all waves done reading cur
  }

  float* Pb = P + (size_t)(MODE == 0 ? (kc << 2) + s : kc) * 65536;
#pragma unroll
  for (int mi = 0; mi < 4; ++mi)
#pragma unroll
    for (int ni = 0; ni < 2; ++ni)
#pragma unroll
      for (int r = 0; r < 4; ++r) {
        int gm = wr * 64 + mi * 16 + fr4 * 4 + r;
        int gn = o0 + wc * 32 + ni * 16 + frow;
        Pb[(size_t)gm * 512 + gn] = acc[mi][ni][r];
      }
#undef STAGE
#undef COMPUTE
}

__global__ __launch_bounds__(256) void reduce2(const float* __restrict__ P2,
                                               f16* __restrict__ A3) {
  int idx = blockIdx.x * 256 + threadIdx.x;  // 262144 = 4s*128b*512o
  int o = idx & 511, b = (idx >> 9) & 127, s = idx >> 16;
  float v = 0.f;
#pragma unroll
  for (int kc = 0; kc < 16; ++kc) v += P2[(size_t)((kc << 2) + s) * 65536 + b * 512 + o];
  v = fmaxf(v * 0.011048543456039805f, 0.f);  // 1/sqrt(8192)
  A3[(size_t)b * 2048 + o * 4 + s] = (f16)v;
}

__global__ __launch_bounds__(256) void out_fused(const float* __restrict__ P3,
                                                 const float* __restrict__ beta,
                                                 float* __restrict__ out) {
  const int b = blockIdx.x, t = threadIdx.x;
  float acc = 0.f;
#pragma unroll
  for (int oi = 0; oi < 2; ++oi) {
    int o = (oi << 8) + t;
    float v = 0.f;
#pragma unroll
    for (int kc = 0; kc < 16; ++kc) v += P3[(size_t)kc * 65536 + b * 512 + o];
    acc += fmaxf(v * 0.022097086912079608f, 0.f) * beta[o];  // 1/sqrt(2048)
  }
  __shared__ float red[4];
#pragma unroll
  for (int off = 32; off > 0; off >>= 1) acc += __shfl_down(acc, off);
  if ((t & 63) == 0) red[t >> 6] = acc;
  __syncthreads();
  if (t == 0) out[b] = (red[0] + red[1] + red[2] + red[3]) * 0.044194173824159216f;
}

extern "C" void kernel_launch(void* const* d_in, const int* in_sizes, int n_in,
                              void* d_out, int out_size, void* d_ws, size_t ws_size,
                              hipStream_t stream) {
  const float* x    = (const float*)d_in[0];
  const float* w1   = (const float*)d_in[1];
  const float* w2   = (const float*)d_in[2];
  const float* w3   = (const float*)d_in[3];
  const float* beta = (const float*)d_in[4];
  float* out = (float*)d_out;

  char* wsb = (char*)d_ws;
  f16*   A2 = (f16*)wsb;                          // 8 MiB: 4*128*8192 fp16
  float* P2 = (float*)(wsb + (8ull << 20));       // 16 MiB: 64*128*512 fp32
  f16*   A3 = (f16*)(wsb + (24ull << 20));        // 0.5 MiB
  float* P3 = (float*)(wsb + (24ull << 20) + (1ull << 19));  // 4 MiB

  l1_mfma<<<dim3(64, 8), 256, 0, stream>>>(x, w1, A2);
  gemm_f16<0><<<512, 256, 0, stream>>>(A2, w2, P2);
  reduce2<<<1024, 256, 0, stream>>>(P2, A3);
  gemm_f16<1><<<128, 256, 0, stream>>>(A3, w3, P3);
  out_fused<<<128, 256, 0, stream>>>(P3, beta, out);
}

// Round 8
// 57.502 us; speedup vs baseline: 1.7711x; 1.0150x over previous
//
#include <hip/hip_runtime.h>

// LocNet2d on MFMA fp16, global_load_lds staging + counted-vmcnt (T4) pipeline.
// L1: per-patch GEMM -> A2 fp16 [s][b][k2=o*16+g]
// L2: per-s GEMM M=128,N=512,K=8192, splitK=16, K-step=64, LDS double-buffered,
//     prefetch-before-compute with s_waitcnt vmcnt(8) (never drain-0 mid-loop).
// L3: same structure, K=2048, splitK=16 -> P3 -> fused reduce+head.

typedef _Float16 f16;
typedef _Float16 half8 __attribute__((ext_vector_type(8)));
typedef _Float16 half4 __attribute__((ext_vector_type(4)));
typedef float f32x4 __attribute__((ext_vector_type(4)));

#define SWZ(r, c) ((((r) << 6) + (c)) ^ (((r) & 7) << 3))

#define GLOAD_LDS16(G, L)                                                     \
  __builtin_amdgcn_global_load_lds(                                           \
      (const __attribute__((address_space(1))) void*)(G),                     \
      (__attribute__((address_space(3))) void*)(L), 16, 0, 0)

__global__ __launch_bounds__(256) void l1_mfma(const float* __restrict__ x,
                                               const float* __restrict__ w1,
                                               f16* __restrict__ A2) {
  const int pq = blockIdx.x, p1 = pq >> 3, q1 = pq & 7;
  const int o0 = blockIdx.y << 6;
  __shared__ __align__(16) f16 Xs[128 * 64];
  __shared__ __align__(16) f16 Ws[64 * 64];
  const int t = threadIdx.x;
#pragma unroll
  for (int i = 0; i < 8; ++i) {
    int idx = (i << 8) + t, row = idx >> 4, j = idx & 15;
    half4 h = {0, 0, 0, 0};
    if (j < 12) {
      float4 v = *(const float4*)(x + ((size_t)row * 3 + (j >> 2)) * 1024 +
                                  (p1 * 4 + (j & 3)) * 32 + q1 * 4);
      h[0] = (f16)v.x; h[1] = (f16)v.y; h[2] = (f16)v.z; h[3] = (f16)v.w;
    }
    *(half4*)&Xs[SWZ(row, j << 2)] = h;
  }
#pragma unroll
  for (int i = 0; i < 4; ++i) {
    int idx = (i << 8) + t, row = idx >> 4, j = idx & 15;
    half4 h = {0, 0, 0, 0};
    if (j < 12) {
      float4 v = *(const float4*)(w1 + (size_t)(o0 + row) * 3072 + (j >> 2) * 1024 +
                                  p1 * 128 + q1 * 16 + (j & 3) * 4);
      h[0] = (f16)v.x; h[1] = (f16)v.y; h[2] = (f16)v.z; h[3] = (f16)v.w;
    }
    *(half4*)&Ws[SWZ(row, j << 2)] = h;
  }
  __syncthreads();
  const int w = t >> 6, lane = t & 63;
  const int wr = w >> 1, wc = w & 1;
  const int frow = lane & 15, fk = (lane >> 4) << 3;
  f32x4 acc[4][2] = {};
#pragma unroll
  for (int ks = 0; ks < 2; ++ks) {
    const int col = (ks << 5) + fk;
    half8 a[4], b[2];
#pragma unroll
    for (int mi = 0; mi < 4; ++mi)
      a[mi] = *(const half8*)&Xs[SWZ(wr * 64 + mi * 16 + frow, col)];
#pragma unroll
    for (int ni = 0; ni < 2; ++ni)
      b[ni] = *(const half8*)&Ws[SWZ(wc * 32 + ni * 16 + frow, col)];
#pragma unroll
    for (int mi = 0; mi < 4; ++mi)
#pragma unroll
      for (int ni = 0; ni < 2; ++ni)
        acc[mi][ni] = __builtin_amdgcn_mfma_f32_16x16x32_f16(a[mi], b[ni], acc[mi][ni], 0, 0, 0);
  }
  const int s2 = ((p1 >> 2) << 1) + (q1 >> 2);
  const int g = ((p1 & 3) << 2) + (q1 & 3);
  f16* A2b = A2 + (size_t)s2 * 128 * 8192;
#pragma unroll
  for (int mi = 0; mi < 4; ++mi)
#pragma unroll
    for (int ni = 0; ni < 2; ++ni)
#pragma unroll
      for (int r = 0; r < 4; ++r) {
        int gm = wr * 64 + mi * 16 + (lane >> 4) * 4 + r;
        int go = o0 + wc * 32 + ni * 16 + (lane & 15);
        float v = fmaxf(acc[mi][ni][r] * 0.14433756729740643f, 0.f);  // 1/sqrt(48)
        A2b[(size_t)gm * 8192 + go * 16 + g] = (f16)v;
      }
}

// MODE 0: L2 (w2 fp32 s-gather, 512 blocks). MODE 1: L3 (w3 fp32 contiguous, 128 blocks).
// Tile M=128 x N=64, K-step 64, double-buffered LDS, counted-vmcnt pipeline:
// each STAGE = 8 global_load_lds/thread; wait vmcnt(8) keeps next tile's loads in
// flight across the barrier (vmcnt(0) only on the last iteration).
template <int MODE>
__global__ __launch_bounds__(256) void gemm_f16(const f16* __restrict__ A,
                                                const float* __restrict__ W,
                                                float* __restrict__ P) {
  __shared__ __align__(16) f16 As[2][128 * 64];   // 2 x 16 KB
  __shared__ __align__(16) float Bs[2][64 * 64];  // 2 x 16 KB
  const int t = threadIdx.x;
  const int bid = blockIdx.x;
  constexpr int AK = (MODE == 0) ? 8192 : 2048;
  constexpr int ITERS = (MODE == 0) ? 8 : 2;  // K-chunk 512 / 128, step 64
  // MODE 0: bid = s*128 + kc*8 + n -> 4 s-blocks of (kc,n) share bid%8 (same XCD).
  const int s = (MODE == 0) ? (bid >> 7) : 0;
  const int kc = (MODE == 0) ? ((bid >> 3) & 15) : (bid >> 3);
  const int n = bid & 7;
  const int kb0 = kc * (ITERS * 64);
  const f16* Ab = A + (size_t)(MODE == 0 ? s * 128 : 0) * AK + kb0;
  const int o0 = n << 6;

  const int wv = t >> 6, ln = t & 63;
  const int a_r = (ln >> 3), a_sg0 = ln & 7;
  const int b_r = (ln >> 4), b_sg0 = ln & 15;

#define STAGE(IT, BUF)                                                          \
  {                                                                             \
    _Pragma("unroll") for (int jj = 0; jj < 4; ++jj) {                          \
      int rbase = wv * 32 + jj * 8;                                             \
      int r = rbase + a_r;                                                      \
      int sg = a_sg0 ^ (r & 7);                                                 \
      GLOAD_LDS16(Ab + (size_t)r * AK + ((IT) << 6) + (sg << 3),                \
                  &As[BUF][rbase << 6]);                                        \
    }                                                                           \
    _Pragma("unroll") for (int jj = 0; jj < 4; ++jj) {                          \
      int rbase = wv * 16 + jj * 4;                                             \
      int r = rbase + b_r;                                                      \
      int sg = b_sg0 ^ (r & 7);                                                 \
      const float* gp;                                                          \
      if constexpr (MODE == 0) {                                                \
        int k = kb0 + ((IT) << 6) + (sg << 2);                                  \
        gp = W + (size_t)(o0 + r) * 32768 + ((k >> 4) << 6) + (s << 4) + (k & 15); \
      } else {                                                                  \
        gp = W + (size_t)(o0 + r) * 2048 + kb0 + ((IT) << 6) + (sg << 2);       \
      }                                                                         \
      GLOAD_LDS16(gp, &Bs[BUF][rbase << 6]);                                    \
    }                                                                           \
  }

  const int wr = wv >> 1, wc = wv & 1;
  const int frow = ln & 15, fr4 = ln >> 4;
  f32x4 acc[4][2] = {};

#define COMPUTE(BUF)                                                            \
  _Pragma("unroll") for (int ks = 0; ks < 2; ++ks) {                            \
    half8 a[4];                                                                 \
    _Pragma("unroll") for (int mi = 0; mi < 4; ++mi) {                          \
      int r = wr * 64 + mi * 16 + frow;                                         \
      int gl = ((ks << 2) + fr4) ^ (r & 7);                                     \
      a[mi] = *(const half8*)&As[BUF][(r << 6) + (gl << 3)];                    \
    }                                                                           \
    _Pragma("unroll") for (int ni = 0; ni < 2; ++ni) {                          \
      int r = wc * 32 + ni * 16 + frow;                                         \
      int s0 = (ks << 3) + (fr4 << 1);                                          \
      float4 f0 = *(const float4*)&Bs[BUF][(r << 6) + ((s0 ^ (r & 7)) << 2)];   \
      float4 f1 = *(const float4*)&Bs[BUF][(r << 6) + (((s0 + 1) ^ (r & 7)) << 2)]; \
      half8 hb;                                                                 \
      hb[0] = (f16)f0.x; hb[1] = (f16)f0.y; hb[2] = (f16)f0.z; hb[3] = (f16)f0.w; \
      hb[4] = (f16)f1.x; hb[5] = (f16)f1.y; hb[6] = (f16)f1.z; hb[7] = (f16)f1.w; \
      _Pragma("unroll") for (int mi = 0; mi < 4; ++mi)                          \
        acc[mi][ni] = __builtin_amdgcn_mfma_f32_16x16x32_f16(a[mi], hb, acc[mi][ni], 0, 0, 0); \
    }                                                                           \
  }

  STAGE(0, 0)
#pragma unroll
  for (int it = 0; it < ITERS; ++it) {
    const int cur = it & 1;
    if (it + 1 < ITERS) {
      STAGE(it + 1, cur ^ 1)  // 8 more in flight (16 total)
      asm volatile("s_waitcnt vmcnt(8)" ::: "memory");  // cur's 8 landed
    } else {
      asm volatile("s_waitcnt vmcnt(0)" ::: "memory");  // last tile: full drain
    }
    __builtin_amdgcn_s_barrier();       // all waves see cur tile in LDS
    __builtin_amdgcn_sched_barrier(0);  // rule 18: no hoist above the wait
    COMPUTE(cur)
    __builtin_amdgcn_sched_barrier(0);
    __builtin_amdgcn_s_barrier();       // all reads done before cur is re-staged
  }

  float* Pb = P + (size_t)(MODE == 0 ? (kc << 2) + s : kc) * 65536;
#pragma unroll
  for (int mi = 0; mi < 4; ++mi)
#pragma unroll
    for (int ni = 0; ni < 2; ++ni)
#pragma unroll
      for (int r = 0; r < 4; ++r) {
        int gm = wr * 64 + mi * 16 + fr4 * 4 + r;
        int gn = o0 + wc * 32 + ni * 16 + frow;
        Pb[(size_t)gm * 512 + gn] = acc[mi][ni][r];
      }
#undef STAGE
#undef COMPUTE
}

__global__ __launch_bounds__(256) void reduce2(const float* __restrict__ P2,
                                               f16* __restrict__ A3) {
  int idx = blockIdx.x * 256 + threadIdx.x;  // 262144 = 4s*128b*512o
  int o = idx & 511, b = (idx >> 9) & 127, s = idx >> 16;
  float v = 0.f;
#pragma unroll
  for (int kc = 0; kc < 16; ++kc) v += P2[(size_t)((kc << 2) + s) * 65536 + b * 512 + o];
  v = fmaxf(v * 0.011048543456039805f, 0.f);  // 1/sqrt(8192)
  A3[(size_t)b * 2048 + o * 4 + s] = (f16)v;
}

__global__ __launch_bounds__(256) void out_fused(const float* __restrict__ P3,
                                                 const float* __restrict__ beta,
                                                 float* __restrict__ out) {
  const int b = blockIdx.x, t = threadIdx.x;
  float acc = 0.f;
#pragma unroll
  for (int oi = 0; oi < 2; ++oi) {
    int o = (oi << 8) + t;
    float v = 0.f;
#pragma unroll
    for (int kc = 0; kc < 16; ++kc) v += P3[(size_t)kc * 65536 + b * 512 + o];
    acc += fmaxf(v * 0.022097086912079608f, 0.f) * beta[o];  // 1/sqrt(2048)
  }
  __shared__ float red[4];
#pragma unroll
  for (int off = 32; off > 0; off >>= 1) acc += __shfl_down(acc, off);
  if ((t & 63) == 0) red[t >> 6] = acc;
  __syncthreads();
  if (t == 0) out[b] = (red[0] + red[1] + red[2] + red[3]) * 0.044194173824159216f;
}

extern "C" void kernel_launch(void* const* d_in, const int* in_sizes, int n_in,
                              void* d_out, int out_size, void* d_ws, size_t ws_size,
                              hipStream_t stream) {
  const float* x    = (const float*)d_in[0];
  const float* w1   = (const float*)d_in[1];
  const float* w2   = (const float*)d_in[2];
  const float* w3   = (const float*)d_in[3];
  const float* beta = (const float*)d_in[4];
  float* out = (float*)d_out;

  char* wsb = (char*)d_ws;
  f16*   A2 = (f16*)wsb;                          // 8 MiB: 4*128*8192 fp16
  float* P2 = (float*)(wsb + (8ull << 20));       // 16 MiB: 64*128*512 fp32
  f16*   A3 = (f16*)(wsb + (24ull << 20));        // 0.5 MiB
  float* P3 = (float*)(wsb + (24ull << 20) + (1ull << 19));  // 4 MiB

  l1_mfma<<<dim3(64, 8), 256, 0, stream>>>(x, w1, A2);
  gemm_f16<0><<<512, 256, 0, stream>>>(A2, w2, P2);
  reduce2<<<1024, 256, 0, stream>>>(P2, A3);
  gemm_f16<1><<<128, 256, 0, stream>>>(A3, w3, P3);
  out_fused<<<128, 256, 0, stream>>>(P3, beta, out);
}